// Round 1
// baseline (1068.067 us; speedup 1.0000x reference)
//
#include <hip/hip_runtime.h>
#include <cstdint>
#include <cstddef>

#define NEGV  -1.0e9f
#define SCALEV 0.125f   // 64^-0.5

// Layouts in workspace (all fp32):
//   Qb: [3][8][8][512][64]   (mod, b, h, n, d)      6291456 elems
//   Kb: [8][8][1536][64]     (b, h, mod*512+n, d)   6291456 elems
//   Vb: same as Kb                                  6291456 elems
//   Ob: [3][4096][512]       (mod, b*512+n, h*64+d) 6291456 elems

// ============================ QKV projection GEMM ============================
// x [4096,512] @ W [512,1536] -> scatter into Qb/Kb/Vb. 128x128 tile, 8x8/thread.
__global__ __launch_bounds__(256) void qkv_gemm(
    const float* __restrict__ x0, const float* __restrict__ x1, const float* __restrict__ x2,
    const float* __restrict__ W0, const float* __restrict__ W1, const float* __restrict__ W2,
    float* __restrict__ Qb, float* __restrict__ Kb, float* __restrict__ Vb)
{
    const int mod = blockIdx.z;
    const float* __restrict__ x = (mod == 0) ? x0 : ((mod == 1) ? x1 : x2);
    const float* __restrict__ W = (mod == 0) ? W0 : ((mod == 1) ? W1 : W2);

    __shared__ float As[16][132];   // [k][m], pad->132 keeps f4 alignment (528B rows)
    __shared__ float Bs[16][132];   // [k][n]

    const int t    = threadIdx.x;
    const int brow = blockIdx.y * 128;   // over M = 4096 (b*512+n)
    const int bcol = blockIdx.x * 128;   // over 1536
    const int rr   = (t >> 4) * 8;
    const int cc   = (t & 15) * 8;

    float acc[8][8];
#pragma unroll
    for (int i = 0; i < 8; i++)
#pragma unroll
        for (int j = 0; j < 8; j++) acc[i][j] = 0.f;

    for (int k0 = 0; k0 < 512; k0 += 16) {
#pragma unroll
        for (int rep = 0; rep < 2; rep++) {
            int f  = t + rep * 256;          // 0..511 float4 slots for A (128x16)
            int m  = f >> 2;
            int kq = (f & 3) << 2;
            float4 v = *reinterpret_cast<const float4*>(&x[(size_t)(brow + m) * 512 + k0 + kq]);
            As[kq + 0][m] = v.x; As[kq + 1][m] = v.y; As[kq + 2][m] = v.z; As[kq + 3][m] = v.w;
        }
#pragma unroll
        for (int rep = 0; rep < 2; rep++) {
            int f = t + rep * 256;           // 0..511 float4 slots for B (16x128)
            int k = f >> 5;
            int n = (f & 31) << 2;
            float4 v = *reinterpret_cast<const float4*>(&W[(size_t)(k0 + k) * 1536 + bcol + n]);
            *reinterpret_cast<float4*>(&Bs[k][n]) = v;
        }
        __syncthreads();
#pragma unroll
        for (int k = 0; k < 16; k++) {
            float a[8], b[8];
#pragma unroll
            for (int j = 0; j < 8; j++) { a[j] = As[k][rr + j]; b[j] = Bs[k][cc + j]; }
#pragma unroll
            for (int i = 0; i < 8; i++)
#pragma unroll
                for (int j = 0; j < 8; j++) acc[i][j] = fmaf(a[i], b[j], acc[i][j]);
        }
        __syncthreads();
    }

    // Epilogue scatter. Whole 128-row stripe is inside one b (512 % 128 == 0),
    // whole 128-col stripe inside one of {q,k,v} (512 % 128 == 0).
    const int b   = brow >> 9;
    const int n0  = brow & 511;
    const int sec = bcol >> 9;                 // 0=q, 1=k, 2=v
    const int cisBase = (bcol - (sec << 9)) + cc;

#pragma unroll
    for (int i = 0; i < 8; i++) {
        const int n = n0 + rr + i;
#pragma unroll
        for (int j = 0; j < 8; j++) {
            const int cis = cisBase + j;
            const int h  = cis >> 6;
            const int dd = cis & 63;
            const float v = acc[i][j];
            if (sec == 0) {
                Qb[((((size_t)mod * 8 + b) * 8 + h) * 512 + n) * 64 + dd] = v;
            } else {
                const int row = mod * 512 + n;
                float* __restrict__ dst = (sec == 1) ? Kb : Vb;
                dst[(((size_t)b * 8 + h) * 1536 + row) * 64 + dd] = v;
            }
        }
    }
}

// ============================ Attention ============================
// One block: (mod, b*8+h, 64-query tile). Online softmax over 1536 keys in
// 64-key chunks. 4x4 microtile per thread; transposed LDS for f4 reads.
__global__ __launch_bounds__(256) void attn_kernel(
    const float* __restrict__ Qb, const float* __restrict__ Kb, const float* __restrict__ Vb,
    const int* __restrict__ m0, const int* __restrict__ m1, const int* __restrict__ m2,
    float* __restrict__ Ob)
{
    const int mod = blockIdx.z;
    const int bh  = blockIdx.y;           // b*8+h
    const int b   = bh >> 3;
    const int h   = bh & 7;
    const int q0  = blockIdx.x * 64;

    __shared__ float QsT[64][68];   // [d][row]
    __shared__ float KsT[64][68];   // [d][key]
    __shared__ float Vs [64][68];   // [key][d]
    __shared__ float PsT[64][68];   // [key][row]

    const int t   = threadIdx.x;
    const int tr4 = (t >> 4) * 4;   // 4 query rows
    const int tc4 = (t & 15) * 4;   // 4 keys (S phase) / 4 dims (PV phase)

    const float* __restrict__ Qp = Qb + ((((size_t)mod * 8 + b) * 8 + h) * 512 + q0) * 64;
    for (int e = t; e < 4096; e += 256) {
        int rr = e >> 6, dd = e & 63;
        QsT[dd][rr] = Qp[(size_t)rr * 64 + dd];
    }

    const int* __restrict__ mk = (mod == 0) ? m0 : ((mod == 1) ? m1 : m2);
    bool maskr[4];
#pragma unroll
    for (int i = 0; i < 4; i++) maskr[i] = mk[b * 512 + q0 + tr4 + i] != 0;

    float mrow[4], lrow[4], o[4][4];
#pragma unroll
    for (int i = 0; i < 4; i++) {
        mrow[i] = -3.0e38f; lrow[i] = 0.f;
#pragma unroll
        for (int j = 0; j < 4; j++) o[i][j] = 0.f;
    }

    const float* __restrict__ Kp = Kb + (size_t)bh * 1536 * 64;
    const float* __restrict__ Vp = Vb + (size_t)bh * 1536 * 64;

    for (int c0 = 0; c0 < 1536; c0 += 64) {
        __syncthreads();   // protect Ks/Vs/PsT from previous iteration readers
        for (int e = t; e < 4096; e += 256) {
            int rr = e >> 6, dd = e & 63;
            float kv = Kp[(size_t)(c0 + rr) * 64 + dd];
            float vv = Vp[(size_t)(c0 + rr) * 64 + dd];
            KsT[dd][rr] = kv;
            Vs[rr][dd]  = vv;
        }
        __syncthreads();

        // S = Q K^T for this 64x64 chunk
        float s[4][4];
#pragma unroll
        for (int i = 0; i < 4; i++)
#pragma unroll
            for (int j = 0; j < 4; j++) s[i][j] = 0.f;
        for (int d = 0; d < 64; d++) {
            float4 a = *reinterpret_cast<const float4*>(&QsT[d][tr4]);
            float4 kk = *reinterpret_cast<const float4*>(&KsT[d][tc4]);
            const float av[4] = {a.x, a.y, a.z, a.w};
            const float kv[4] = {kk.x, kk.y, kk.z, kk.w};
#pragma unroll
            for (int i = 0; i < 4; i++)
#pragma unroll
                for (int j = 0; j < 4; j++) s[i][j] = fmaf(av[i], kv[j], s[i][j]);
        }
#pragma unroll
        for (int i = 0; i < 4; i++)
#pragma unroll
            for (int j = 0; j < 4; j++) {
                s[i][j] *= SCALEV;
                if (!maskr[i]) s[i][j] = NEGV;
            }

        // online softmax update
        float ps[4][4];
#pragma unroll
        for (int i = 0; i < 4; i++) {
            float cm = fmaxf(fmaxf(s[i][0], s[i][1]), fmaxf(s[i][2], s[i][3]));
#pragma unroll
            for (int off = 1; off < 16; off <<= 1) cm = fmaxf(cm, __shfl_xor(cm, off));
            const float mn = fmaxf(mrow[i], cm);
            const float sc = __expf(mrow[i] - mn);
            mrow[i] = mn;
            float r = 0.f;
#pragma unroll
            for (int j = 0; j < 4; j++) { ps[i][j] = __expf(s[i][j] - mn); r += ps[i][j]; }
#pragma unroll
            for (int off = 1; off < 16; off <<= 1) r += __shfl_xor(r, off);
            lrow[i] = lrow[i] * sc + r;
#pragma unroll
            for (int j = 0; j < 4; j++) o[i][j] *= sc;
        }
#pragma unroll
        for (int i = 0; i < 4; i++)
#pragma unroll
            for (int j = 0; j < 4; j++) PsT[tc4 + j][tr4 + i] = ps[i][j];
        __syncthreads();

        // O += P V  (tc4 now indexes dims)
        for (int c = 0; c < 64; c++) {
            float4 a = *reinterpret_cast<const float4*>(&PsT[c][tr4]);
            float4 vv = *reinterpret_cast<const float4*>(&Vs[c][tc4]);
            const float av[4] = {a.x, a.y, a.z, a.w};
            const float bv[4] = {vv.x, vv.y, vv.z, vv.w};
#pragma unroll
            for (int i = 0; i < 4; i++)
#pragma unroll
                for (int j = 0; j < 4; j++) o[i][j] = fmaf(av[i], bv[j], o[i][j]);
        }
    }

#pragma unroll
    for (int i = 0; i < 4; i++) {
        const float inv = 1.f / lrow[i];
        const size_t base = ((size_t)mod * 4096 + b * 512 + q0 + tr4 + i) * 512 + h * 64 + tc4;
#pragma unroll
        for (int j = 0; j < 4; j++) Ob[base + j] = o[i][j] * inv;
    }
}

// ============================ Output projection GEMM ============================
// Ob[mod] [4096,512] @ Wout[mod] [512,512] -> d_out + mod*4096*512
__global__ __launch_bounds__(256) void out_gemm(
    const float* __restrict__ Ob,
    const float* __restrict__ Wo0, const float* __restrict__ Wo1, const float* __restrict__ Wo2,
    float* __restrict__ out)
{
    const int mod = blockIdx.z;
    const float* __restrict__ A = Ob + (size_t)mod * 4096 * 512;
    const float* __restrict__ W = (mod == 0) ? Wo0 : ((mod == 1) ? Wo1 : Wo2);
    float* __restrict__ C = out + (size_t)mod * 4096 * 512;

    __shared__ float As[16][132];
    __shared__ float Bs[16][132];

    const int t    = threadIdx.x;
    const int brow = blockIdx.y * 128;
    const int bcol = blockIdx.x * 128;
    const int rr   = (t >> 4) * 8;
    const int cc   = (t & 15) * 8;

    float acc[8][8];
#pragma unroll
    for (int i = 0; i < 8; i++)
#pragma unroll
        for (int j = 0; j < 8; j++) acc[i][j] = 0.f;

    for (int k0 = 0; k0 < 512; k0 += 16) {
#pragma unroll
        for (int rep = 0; rep < 2; rep++) {
            int f  = t + rep * 256;
            int m  = f >> 2;
            int kq = (f & 3) << 2;
            float4 v = *reinterpret_cast<const float4*>(&A[(size_t)(brow + m) * 512 + k0 + kq]);
            As[kq + 0][m] = v.x; As[kq + 1][m] = v.y; As[kq + 2][m] = v.z; As[kq + 3][m] = v.w;
        }
#pragma unroll
        for (int rep = 0; rep < 2; rep++) {
            int f = t + rep * 256;
            int k = f >> 5;
            int n = (f & 31) << 2;
            float4 v = *reinterpret_cast<const float4*>(&W[(size_t)(k0 + k) * 512 + bcol + n]);
            *reinterpret_cast<float4*>(&Bs[k][n]) = v;
        }
        __syncthreads();
#pragma unroll
        for (int k = 0; k < 16; k++) {
            float a[8], bq[8];
#pragma unroll
            for (int j = 0; j < 8; j++) { a[j] = As[k][rr + j]; bq[j] = Bs[k][cc + j]; }
#pragma unroll
            for (int i = 0; i < 8; i++)
#pragma unroll
                for (int j = 0; j < 8; j++) acc[i][j] = fmaf(a[i], bq[j], acc[i][j]);
        }
        __syncthreads();
    }

#pragma unroll
    for (int i = 0; i < 8; i++) {
        const size_t base = (size_t)(brow + rr + i) * 512 + bcol + cc;
#pragma unroll
        for (int j = 0; j < 8; j++) C[base + j] = acc[i][j];
    }
}

extern "C" void kernel_launch(void* const* d_in, const int* in_sizes, int n_in,
                              void* d_out, int out_size, void* d_ws, size_t ws_size,
                              hipStream_t stream)
{
    // setup_inputs insertion order is INTERLEAVED per modality:
    //   x0, m0, Wqkv0, Wout0, x1, m1, Wqkv1, Wout1, x2, m2, Wqkv2, Wout2
    const float* x0  = (const float*)d_in[0];
    const int*   m0  = (const int*)  d_in[1];
    const float* Wq0 = (const float*)d_in[2];
    const float* Wo0 = (const float*)d_in[3];
    const float* x1  = (const float*)d_in[4];
    const int*   m1  = (const int*)  d_in[5];
    const float* Wq1 = (const float*)d_in[6];
    const float* Wo1 = (const float*)d_in[7];
    const float* x2  = (const float*)d_in[8];
    const int*   m2  = (const int*)  d_in[9];
    const float* Wq2 = (const float*)d_in[10];
    const float* Wo2 = (const float*)d_in[11];

    float* Qb = (float*)d_ws;                // 6291456 floats
    float* Kb = Qb + 6291456;
    float* Vb = Kb + 6291456;
    float* Ob = Vb + 6291456;

    qkv_gemm<<<dim3(12, 32, 3), 256, 0, stream>>>(x0, x1, x2, Wq0, Wq1, Wq2, Qb, Kb, Vb);
    attn_kernel<<<dim3(8, 64, 3), 256, 0, stream>>>(Qb, Kb, Vb, m0, m1, m2, Ob);
    out_gemm<<<dim3(4, 32, 3), 256, 0, stream>>>(Ob, Wo0, Wo1, Wo2, (float*)d_out);
}

// Round 2
// 346.994 us; speedup vs baseline: 3.0781x; 3.0781x over previous
//
#include <hip/hip_runtime.h>
#include <cstdint>
#include <cstddef>

#define NEGV  -1.0e9f

typedef _Float16 h8 __attribute__((ext_vector_type(8)));
typedef _Float16 h4 __attribute__((ext_vector_type(4)));
typedef float    f4 __attribute__((ext_vector_type(4)));

// ---------------------------------------------------------------------------
// ws layout (f16 elements):
//  xh : [3][4096][512]          6291456
//  Wqt: [3][1536][512]  (W^T)   2359296
//  Wot: [3][512][512]   (W^T)    786432
//  Qh : [3][8][8][512][64] (q*0.125)  6291456
//  Kh : [8][8][1536][64]        6291456
//  Vt : [8][8][64][1536] (V^T)  6291456
//  Oh : [3][4096][512]          6291456
// total ~69 MB
// ---------------------------------------------------------------------------

// ======================= conversion: x -> f16 =======================
__global__ __launch_bounds__(256) void cvt_x(
    const float* __restrict__ x0, const float* __restrict__ x1, const float* __restrict__ x2,
    _Float16* __restrict__ xh)
{
    const int mod = blockIdx.y;
    const float* __restrict__ s = (mod == 0) ? x0 : ((mod == 1) ? x1 : x2);
    _Float16* __restrict__ d = xh + (size_t)mod * 2097152;
    const int i = (blockIdx.x * 256 + threadIdx.x) * 4;
    float4 v = *reinterpret_cast<const float4*>(&s[i]);
    h4 o = { (_Float16)v.x, (_Float16)v.y, (_Float16)v.z, (_Float16)v.w };
    *reinterpret_cast<h4*>(&d[i]) = o;
}

// ============== conversion: W [R][C] f32 -> W^T [C][R] f16 ==============
__global__ __launch_bounds__(256) void tr_cvt(
    const float* __restrict__ s0, const float* __restrict__ s1, const float* __restrict__ s2,
    _Float16* __restrict__ dst, int R, int C)
{
    const int mod = blockIdx.z;
    const float* __restrict__ s = (mod == 0) ? s0 : ((mod == 1) ? s1 : s2);
    _Float16* __restrict__ d = dst + (size_t)mod * R * C;
    const int c0 = blockIdx.x * 32, r0 = blockIdx.y * 32;
    __shared__ float tile[32][33];
    const int tr = threadIdx.x >> 3;
    const int tc = (threadIdx.x & 7) * 4;
    float4 v = *reinterpret_cast<const float4*>(&s[(size_t)(r0 + tr) * C + c0 + tc]);
    tile[tr][tc + 0] = v.x; tile[tr][tc + 1] = v.y; tile[tr][tc + 2] = v.z; tile[tr][tc + 3] = v.w;
    __syncthreads();
    h4 o = { (_Float16)tile[tc + 0][tr], (_Float16)tile[tc + 1][tr],
             (_Float16)tile[tc + 2][tr], (_Float16)tile[tc + 3][tr] };
    *reinterpret_cast<h4*>(&d[(size_t)(c0 + tr) * R + r0 + tc]) = o;
}

// ======================= QKV projection (f16 MFMA) =======================
// xh[mod] [4096][512] @ Wqt[mod]^T -> scatter Qh/Kh/Vt. 128x128 tile, BK=32.
__global__ __launch_bounds__(256) void qkv_gemm_f16(
    const _Float16* __restrict__ xh, const _Float16* __restrict__ Wqt,
    _Float16* __restrict__ Qh, _Float16* __restrict__ Kh, _Float16* __restrict__ Vt)
{
    const int mod = blockIdx.z;
    const _Float16* __restrict__ A  = xh  + (size_t)mod * 4096 * 512;
    const _Float16* __restrict__ Bw = Wqt + (size_t)mod * 1536 * 512;

    __shared__ _Float16 As[128 * 40];   // [m][k], pad 8 -> 2-way bank alias (free)
    __shared__ _Float16 Bs[128 * 40];   // [n][k]

    const int t = threadIdx.x;
    const int brow = blockIdx.y * 128, bcol = blockIdx.x * 128;
    const int w = t >> 6, l = t & 63;
    const int wr = (w >> 1) * 64, wc = (w & 1) * 64;
    const int lr = l & 15, lk = (l >> 4) * 8, lg = l >> 4;

    f4 acc[4][4] = {};

    for (int k0 = 0; k0 < 512; k0 += 32) {
        if (k0) __syncthreads();
#pragma unroll
        for (int rep = 0; rep < 2; rep++) {
            const int idx = t + rep * 256;       // 0..511
            const int m = idx >> 2, kk = (idx & 3) << 3;
            *reinterpret_cast<h8*>(&As[m * 40 + kk]) =
                *reinterpret_cast<const h8*>(&A[(size_t)(brow + m) * 512 + k0 + kk]);
            *reinterpret_cast<h8*>(&Bs[m * 40 + kk]) =
                *reinterpret_cast<const h8*>(&Bw[(size_t)(bcol + m) * 512 + k0 + kk]);
        }
        __syncthreads();
        h8 af[4], bf[4];
#pragma unroll
        for (int m = 0; m < 4; m++)
            af[m] = *reinterpret_cast<h8*>(&As[(wr + m * 16 + lr) * 40 + lk]);
#pragma unroll
        for (int n = 0; n < 4; n++)
            bf[n] = *reinterpret_cast<h8*>(&Bs[(wc + n * 16 + lr) * 40 + lk]);
#pragma unroll
        for (int m = 0; m < 4; m++)
#pragma unroll
            for (int n = 0; n < 4; n++)
                acc[m][n] = __builtin_amdgcn_mfma_f32_16x16x32_f16(af[m], bf[n], acc[m][n], 0, 0, 0);
    }

    // epilogue scatter (C layout: row=(l>>4)*4+reg, col=l&15)
    const int sec = bcol >> 9;                    // 0=q 1=k 2=v
    const int b = brow >> 9;
    const int nbase = brow & 511;
    const int cbase = bcol - (sec << 9);

#pragma unroll
    for (int m = 0; m < 4; m++) {
        const int rloc = wr + m * 16 + lg * 4;
#pragma unroll
        for (int reg = 0; reg < 4; reg++) {
            const int n = nbase + rloc + reg;
#pragma unroll
            for (int nn = 0; nn < 4; nn++) {
                const int cis = cbase + wc + nn * 16 + lr;
                const int h = cis >> 6, d = cis & 63;
                const float v = acc[m][nn][reg];
                if (sec == 0) {
                    Qh[((((size_t)mod * 8 + b) * 8 + h) * 512 + n) * 64 + d] = (_Float16)(v * 0.125f);
                } else if (sec == 1) {
                    Kh[(((size_t)b * 8 + h) * 1536 + mod * 512 + n) * 64 + d] = (_Float16)v;
                } else {
                    Vt[(((size_t)b * 8 + h) * 64 + d) * 1536 + mod * 512 + n] = (_Float16)v;
                }
            }
        }
    }
}

// ======================= attention (f16 MFMA, online softmax) =======================
// block: (q-tile of 64, bh, mod); 4 waves, wave w owns 16 q-rows.
__global__ __launch_bounds__(256) void attn_f16(
    const _Float16* __restrict__ Qh, const _Float16* __restrict__ Kh, const _Float16* __restrict__ Vt,
    const int* __restrict__ m0, const int* __restrict__ m1, const int* __restrict__ m2,
    _Float16* __restrict__ Oh)
{
    const int mod = blockIdx.z;
    const int bh = blockIdx.y, b = bh >> 3, h = bh & 7;
    const int q0 = blockIdx.x * 64;

    __shared__ _Float16 Ks[64 * 72];   // [key][d]
    __shared__ _Float16 Vs[64 * 72];   // [d][key]
    __shared__ _Float16 Ps[64 * 72];   // [q][key] (wave-local rows)

    const int t = threadIdx.x, w = t >> 6, l = t & 63;
    const int lr = l & 15, lk = (l >> 4) * 8, lg = l >> 4;

    const _Float16* __restrict__ Qp = Qh + ((((size_t)mod * 8 + b) * 8 + h) * 512 + q0 + w * 16) * 64;
    h8 qf[2];
    qf[0] = *reinterpret_cast<const h8*>(&Qp[(size_t)lr * 64 + lk]);
    qf[1] = *reinterpret_cast<const h8*>(&Qp[(size_t)lr * 64 + 32 + lk]);

    const int* __restrict__ mk = (mod == 0) ? m0 : ((mod == 1) ? m1 : m2);
    bool msk[4];
#pragma unroll
    for (int reg = 0; reg < 4; reg++)
        msk[reg] = mk[b * 512 + q0 + w * 16 + lg * 4 + reg] != 0;

    float mrow[4] = { -3.0e38f, -3.0e38f, -3.0e38f, -3.0e38f };
    float lsum[4] = { 0.f, 0.f, 0.f, 0.f };
    f4 o[4] = {};

    const _Float16* __restrict__ Kp = Kh + (size_t)bh * 1536 * 64;
    const _Float16* __restrict__ Vp = Vt + (size_t)bh * 64 * 1536;

    for (int c0 = 0; c0 < 1536; c0 += 64) {
        __syncthreads();
#pragma unroll
        for (int rep = 0; rep < 2; rep++) {
            const int idx = t + rep * 256;       // 0..511
            const int r = idx >> 3, kk = (idx & 7) << 3;
            *reinterpret_cast<h8*>(&Ks[r * 72 + kk]) =
                *reinterpret_cast<const h8*>(&Kp[(size_t)(c0 + r) * 64 + kk]);
            *reinterpret_cast<h8*>(&Vs[r * 72 + kk]) =
                *reinterpret_cast<const h8*>(&Vp[(size_t)r * 1536 + c0 + kk]);
        }
        __syncthreads();

        // S = (Q*scale) K^T, 16q x 64k per wave
        f4 s[4] = {};
#pragma unroll
        for (int kg = 0; kg < 4; kg++) {
            h8 k0f = *reinterpret_cast<h8*>(&Ks[(kg * 16 + lr) * 72 + lk]);
            h8 k1f = *reinterpret_cast<h8*>(&Ks[(kg * 16 + lr) * 72 + 32 + lk]);
            s[kg] = __builtin_amdgcn_mfma_f32_16x16x32_f16(qf[0], k0f, s[kg], 0, 0, 0);
            s[kg] = __builtin_amdgcn_mfma_f32_16x16x32_f16(qf[1], k1f, s[kg], 0, 0, 0);
        }

        // online softmax (row stats per (lg,reg); 16-lane butterfly over keys)
#pragma unroll
        for (int reg = 0; reg < 4; reg++) {
            float v0 = s[0][reg], v1 = s[1][reg], v2 = s[2][reg], v3 = s[3][reg];
            if (!msk[reg]) { v0 = NEGV; v1 = NEGV; v2 = NEGV; v3 = NEGV; }
            float cm = fmaxf(fmaxf(v0, v1), fmaxf(v2, v3));
#pragma unroll
            for (int off = 1; off < 16; off <<= 1) cm = fmaxf(cm, __shfl_xor(cm, off));
            const float mn = fmaxf(mrow[reg], cm);
            const float sc = __expf(mrow[reg] - mn);
            mrow[reg] = mn;
            const float pv[4] = { v0, v1, v2, v3 };
            float rs = 0.f;
#pragma unroll
            for (int kg = 0; kg < 4; kg++) {
                const _Float16 ph = (_Float16)__expf(pv[kg] - mn);
                Ps[(size_t)(w * 16 + lg * 4 + reg) * 72 + kg * 16 + lr] = ph;
                rs += (float)ph;
            }
#pragma unroll
            for (int off = 1; off < 16; off <<= 1) rs += __shfl_xor(rs, off);
            lsum[reg] = lsum[reg] * sc + rs;
            o[0][reg] *= sc; o[1][reg] *= sc; o[2][reg] *= sc; o[3][reg] *= sc;
        }

        // O += P V  (Ps rows are wave-local: in-order DS ops within a wave, no barrier)
#pragma unroll
        for (int kb = 0; kb < 2; kb++) {
            h8 pa = *reinterpret_cast<h8*>(&Ps[(w * 16 + lr) * 72 + kb * 32 + lk]);
#pragma unroll
            for (int dg = 0; dg < 4; dg++) {
                h8 vb = *reinterpret_cast<h8*>(&Vs[(dg * 16 + lr) * 72 + kb * 32 + lk]);
                o[dg] = __builtin_amdgcn_mfma_f32_16x16x32_f16(pa, vb, o[dg], 0, 0, 0);
            }
        }
    }

    const size_t rowg = (size_t)mod * 4096 + b * 512 + q0 + w * 16 + lg * 4;
#pragma unroll
    for (int reg = 0; reg < 4; reg++) {
        const float inv = 1.f / lsum[reg];
#pragma unroll
        for (int dg = 0; dg < 4; dg++)
            Oh[(rowg + reg) * 512 + h * 64 + dg * 16 + lr] = (_Float16)(o[dg][reg] * inv);
    }
}

// ======================= output projection (f16 MFMA, f32 out) =======================
__global__ __launch_bounds__(256) void out_gemm_f16(
    const _Float16* __restrict__ Oh, const _Float16* __restrict__ Wot,
    float* __restrict__ out)
{
    const int mod = blockIdx.z;
    const _Float16* __restrict__ A  = Oh  + (size_t)mod * 4096 * 512;
    const _Float16* __restrict__ Bw = Wot + (size_t)mod * 512 * 512;
    float* __restrict__ C = out + (size_t)mod * 4096 * 512;

    __shared__ _Float16 As[128 * 40];
    __shared__ _Float16 Bs[128 * 40];

    const int t = threadIdx.x;
    const int brow = blockIdx.y * 128, bcol = blockIdx.x * 128;
    const int w = t >> 6, l = t & 63;
    const int wr = (w >> 1) * 64, wc = (w & 1) * 64;
    const int lr = l & 15, lk = (l >> 4) * 8, lg = l >> 4;

    f4 acc[4][4] = {};

    for (int k0 = 0; k0 < 512; k0 += 32) {
        if (k0) __syncthreads();
#pragma unroll
        for (int rep = 0; rep < 2; rep++) {
            const int idx = t + rep * 256;
            const int m = idx >> 2, kk = (idx & 3) << 3;
            *reinterpret_cast<h8*>(&As[m * 40 + kk]) =
                *reinterpret_cast<const h8*>(&A[(size_t)(brow + m) * 512 + k0 + kk]);
            *reinterpret_cast<h8*>(&Bs[m * 40 + kk]) =
                *reinterpret_cast<const h8*>(&Bw[(size_t)(bcol + m) * 512 + k0 + kk]);
        }
        __syncthreads();
        h8 af[4], bf[4];
#pragma unroll
        for (int m = 0; m < 4; m++)
            af[m] = *reinterpret_cast<h8*>(&As[(wr + m * 16 + lr) * 40 + lk]);
#pragma unroll
        for (int n = 0; n < 4; n++)
            bf[n] = *reinterpret_cast<h8*>(&Bs[(wc + n * 16 + lr) * 40 + lk]);
#pragma unroll
        for (int m = 0; m < 4; m++)
#pragma unroll
            for (int n = 0; n < 4; n++)
                acc[m][n] = __builtin_amdgcn_mfma_f32_16x16x32_f16(af[m], bf[n], acc[m][n], 0, 0, 0);
    }

#pragma unroll
    for (int m = 0; m < 4; m++) {
        const int rloc = wr + m * 16 + lg * 4;
#pragma unroll
        for (int reg = 0; reg < 4; reg++) {
            const size_t base = (size_t)(brow + rloc + reg) * 512 + bcol;
#pragma unroll
            for (int nn = 0; nn < 4; nn++)
                C[base + wc + nn * 16 + lr] = acc[m][nn][reg];
        }
    }
}

extern "C" void kernel_launch(void* const* d_in, const int* in_sizes, int n_in,
                              void* d_out, int out_size, void* d_ws, size_t ws_size,
                              hipStream_t stream)
{
    // interleaved inputs: x0,m0,Wqkv0,Wout0, x1,m1,Wqkv1,Wout1, x2,m2,Wqkv2,Wout2
    const float* x0  = (const float*)d_in[0];
    const int*   m0  = (const int*)  d_in[1];
    const float* Wq0 = (const float*)d_in[2];
    const float* Wo0 = (const float*)d_in[3];
    const float* x1  = (const float*)d_in[4];
    const int*   m1  = (const int*)  d_in[5];
    const float* Wq1 = (const float*)d_in[6];
    const float* Wo1 = (const float*)d_in[7];
    const float* x2  = (const float*)d_in[8];
    const int*   m2  = (const int*)  d_in[9];
    const float* Wq2 = (const float*)d_in[10];
    const float* Wo2 = (const float*)d_in[11];

    _Float16* xh  = (_Float16*)d_ws;       // 6291456
    _Float16* Wqt = xh  + 6291456;         // 2359296
    _Float16* Wot = Wqt + 2359296;         //  786432
    _Float16* Qh  = Wot + 786432;          // 6291456
    _Float16* Kh  = Qh  + 6291456;         // 6291456
    _Float16* Vt  = Kh  + 6291456;         // 6291456
    _Float16* Oh  = Vt  + 6291456;         // 6291456

    cvt_x <<<dim3(2048, 3), 256, 0, stream>>>(x0, x1, x2, xh);
    tr_cvt<<<dim3(48, 16, 3), 256, 0, stream>>>(Wq0, Wq1, Wq2, Wqt, 512, 1536);
    tr_cvt<<<dim3(16, 16, 3), 256, 0, stream>>>(Wo0, Wo1, Wo2, Wot, 512, 512);

    qkv_gemm_f16<<<dim3(12, 32, 3), 256, 0, stream>>>(xh, Wqt, Qh, Kh, Vt);
    attn_f16    <<<dim3(8, 64, 3), 256, 0, stream>>>(Qh, Kh, Vt, m0, m1, m2, Oh);
    out_gemm_f16<<<dim3(4, 32, 3), 256, 0, stream>>>(Oh, Wot, (float*)d_out);
}

// Round 3
// 266.627 us; speedup vs baseline: 4.0058x; 1.3014x over previous
//
#include <hip/hip_runtime.h>
#include <cstdint>
#include <cstddef>

#define NEGV  -1.0e9f
// 0.125 * log2(e): attention computed in exp2 units
#define QSCALE 0.18033688011112042f

typedef _Float16 h8 __attribute__((ext_vector_type(8)));
typedef _Float16 h4 __attribute__((ext_vector_type(4)));
typedef float    f4 __attribute__((ext_vector_type(4)));

// ---------------------------------------------------------------------------
// ws layout (f16 elements):
//  xh : [3][4096][512]          6291456
//  Wqt: [3][1536][512]  (W^T)   2359296
//  Wot: [3][512][512]   (W^T)    786432
//  Qh : [3][8][8][512][64] (q*QSCALE)  6291456
//  Kh : [8][8][1536][64]        6291456
//  Vt : [8][8][64][1536] (V^T)  6291456
//  Oh : [3][4096][512]          6291456
// ---------------------------------------------------------------------------

// ======================= conversion: x -> f16 =======================
__global__ __launch_bounds__(256) void cvt_x(
    const float* __restrict__ x0, const float* __restrict__ x1, const float* __restrict__ x2,
    _Float16* __restrict__ xh)
{
    const int mod = blockIdx.y;
    const float* __restrict__ s = (mod == 0) ? x0 : ((mod == 1) ? x1 : x2);
    _Float16* __restrict__ d = xh + (size_t)mod * 2097152;
    const int i = (blockIdx.x * 256 + threadIdx.x) * 4;
    float4 v = *reinterpret_cast<const float4*>(&s[i]);
    h4 o = { (_Float16)v.x, (_Float16)v.y, (_Float16)v.z, (_Float16)v.w };
    *reinterpret_cast<h4*>(&d[i]) = o;
}

// ============== conversion: W [R][C] f32 -> W^T [C][R] f16 ==============
__global__ __launch_bounds__(256) void tr_cvt(
    const float* __restrict__ s0, const float* __restrict__ s1, const float* __restrict__ s2,
    _Float16* __restrict__ dst, int R, int C)
{
    const int mod = blockIdx.z;
    const float* __restrict__ s = (mod == 0) ? s0 : ((mod == 1) ? s1 : s2);
    _Float16* __restrict__ d = dst + (size_t)mod * R * C;
    const int c0 = blockIdx.x * 32, r0 = blockIdx.y * 32;
    __shared__ float tile[32][33];
    const int tr = threadIdx.x >> 3;
    const int tc = (threadIdx.x & 7) * 4;
    float4 v = *reinterpret_cast<const float4*>(&s[(size_t)(r0 + tr) * C + c0 + tc]);
    tile[tr][tc + 0] = v.x; tile[tr][tc + 1] = v.y; tile[tr][tc + 2] = v.z; tile[tr][tc + 3] = v.w;
    __syncthreads();
    h4 o = { (_Float16)tile[tc + 0][tr], (_Float16)tile[tc + 1][tr],
             (_Float16)tile[tc + 2][tr], (_Float16)tile[tc + 3][tr] };
    *reinterpret_cast<h4*>(&d[(size_t)(c0 + tr) * R + r0 + tc]) = o;
}

// ======================= QKV projection (f16 MFMA) =======================
// xh[mod] [4096][512] @ Wqt[mod]^T -> scatter Qh/Kh/Vt. 128x128 tile, BK=32,
// register-prefetched staging (issue-early / write-late).
__global__ __launch_bounds__(256) void qkv_gemm_f16(
    const _Float16* __restrict__ xh, const _Float16* __restrict__ Wqt,
    _Float16* __restrict__ Qh, _Float16* __restrict__ Kh, _Float16* __restrict__ Vt)
{
    const int mod = blockIdx.z;
    const _Float16* __restrict__ A  = xh  + (size_t)mod * 4096 * 512;
    const _Float16* __restrict__ Bw = Wqt + (size_t)mod * 1536 * 512;

    __shared__ _Float16 As[128 * 40];   // [m][k], stride 80B -> even bank spread
    __shared__ _Float16 Bs[128 * 40];   // [n][k]

    const int t = threadIdx.x;
    const int brow = blockIdx.y * 128, bcol = blockIdx.x * 128;
    const int w = t >> 6, l = t & 63;
    const int wr = (w >> 1) * 64, wc = (w & 1) * 64;
    const int lr = l & 15, lk = (l >> 4) * 8, lg = l >> 4;

    // staging slots: idx = t + rep*256 in [0,512); m = idx>>2, kk = (idx&3)*8
    const int sm0 = t >> 2,        skk = (t & 3) * 8;
    const int sm1 = (t + 256) >> 2;

    f4 acc[4][4] = {};
    h8 arg[2], brg[2];

    arg[0] = *reinterpret_cast<const h8*>(&A [(size_t)(brow + sm0) * 512 + skk]);
    arg[1] = *reinterpret_cast<const h8*>(&A [(size_t)(brow + sm1) * 512 + skk]);
    brg[0] = *reinterpret_cast<const h8*>(&Bw[(size_t)(bcol + sm0) * 512 + skk]);
    brg[1] = *reinterpret_cast<const h8*>(&Bw[(size_t)(bcol + sm1) * 512 + skk]);
    *reinterpret_cast<h8*>(&As[sm0 * 40 + skk]) = arg[0];
    *reinterpret_cast<h8*>(&As[sm1 * 40 + skk]) = arg[1];
    *reinterpret_cast<h8*>(&Bs[sm0 * 40 + skk]) = brg[0];
    *reinterpret_cast<h8*>(&Bs[sm1 * 40 + skk]) = brg[1];

    for (int k0 = 0; k0 < 512; k0 += 32) {
        __syncthreads();
        const bool more = (k0 + 32) < 512;
        if (more) {
            const int kn = k0 + 32;
            arg[0] = *reinterpret_cast<const h8*>(&A [(size_t)(brow + sm0) * 512 + kn + skk]);
            arg[1] = *reinterpret_cast<const h8*>(&A [(size_t)(brow + sm1) * 512 + kn + skk]);
            brg[0] = *reinterpret_cast<const h8*>(&Bw[(size_t)(bcol + sm0) * 512 + kn + skk]);
            brg[1] = *reinterpret_cast<const h8*>(&Bw[(size_t)(bcol + sm1) * 512 + kn + skk]);
        }
        h8 af[4], bf[4];
#pragma unroll
        for (int m = 0; m < 4; m++)
            af[m] = *reinterpret_cast<h8*>(&As[(wr + m * 16 + lr) * 40 + lk]);
#pragma unroll
        for (int n = 0; n < 4; n++)
            bf[n] = *reinterpret_cast<h8*>(&Bs[(wc + n * 16 + lr) * 40 + lk]);
        __builtin_amdgcn_s_setprio(1);
#pragma unroll
        for (int m = 0; m < 4; m++)
#pragma unroll
            for (int n = 0; n < 4; n++)
                acc[m][n] = __builtin_amdgcn_mfma_f32_16x16x32_f16(af[m], bf[n], acc[m][n], 0, 0, 0);
        __builtin_amdgcn_s_setprio(0);
        __syncthreads();
        if (more) {
            *reinterpret_cast<h8*>(&As[sm0 * 40 + skk]) = arg[0];
            *reinterpret_cast<h8*>(&As[sm1 * 40 + skk]) = arg[1];
            *reinterpret_cast<h8*>(&Bs[sm0 * 40 + skk]) = brg[0];
            *reinterpret_cast<h8*>(&Bs[sm1 * 40 + skk]) = brg[1];
        }
    }

    // epilogue scatter (C layout: row=(l>>4)*4+reg, col=l&15)
    const int sec = bcol >> 9;                    // 0=q 1=k 2=v
    const int b = brow >> 9;
    const int nbase = brow & 511;
    const int cbase = bcol - (sec << 9);

#pragma unroll
    for (int m = 0; m < 4; m++) {
        const int rloc = wr + m * 16 + lg * 4;
#pragma unroll
        for (int reg = 0; reg < 4; reg++) {
            const int n = nbase + rloc + reg;
#pragma unroll
            for (int nn = 0; nn < 4; nn++) {
                const int cis = cbase + wc + nn * 16 + lr;
                const int h = cis >> 6, d = cis & 63;
                const float v = acc[m][nn][reg];
                if (sec == 0) {
                    Qh[((((size_t)mod * 8 + b) * 8 + h) * 512 + n) * 64 + d] = (_Float16)(v * QSCALE);
                } else if (sec == 1) {
                    Kh[(((size_t)b * 8 + h) * 1536 + mod * 512 + n) * 64 + d] = (_Float16)v;
                } else {
                    Vt[(((size_t)b * 8 + h) * 64 + d) * 1536 + mod * 512 + n] = (_Float16)v;
                }
            }
        }
    }
}

// ======================= attention (swapped QK^T, lane-local softmax) =======================
// block: (q-tile of 64, bh, mod); 4 waves, wave w owns queries q0+w*16 .. +15.
// Each lane owns ONE query row (q = lane&15) and 16 keys per 64-key chunk.
__global__ __launch_bounds__(256) void attn_f16(
    const _Float16* __restrict__ Qh, const _Float16* __restrict__ Kh, const _Float16* __restrict__ Vt,
    const int* __restrict__ m0, const int* __restrict__ m1, const int* __restrict__ m2,
    _Float16* __restrict__ Oh)
{
    const int mod = blockIdx.z;
    const int bh = blockIdx.y, b = bh >> 3, h = bh & 7;
    const int q0 = blockIdx.x * 64;

    __shared__ _Float16 Ks[64 * 72];   // [key][d]
    __shared__ _Float16 Vs[64 * 72];   // [d][key]
    __shared__ _Float16 Ps[64 * 72];   // [q][key] (wave-local rows)

    const int t = threadIdx.x, w = t >> 6, l = t & 63;
    const int lr = l & 15, lg = l >> 4, lk = lg * 8;

    // Q B-frag: lane holds Q[q=lr][d=lk..lk+7] (+32 for second K-half)
    const _Float16* __restrict__ Qp = Qh + ((((size_t)mod * 8 + b) * 8 + h) * 512 + q0 + w * 16) * 64;
    h8 qf0 = *reinterpret_cast<const h8*>(&Qp[(size_t)lr * 64 + lk]);
    h8 qf1 = *reinterpret_cast<const h8*>(&Qp[(size_t)lr * 64 + 32 + lk]);

    const int* __restrict__ mk = (mod == 0) ? m0 : ((mod == 1) ? m1 : m2);
    const bool msk = mk[b * 512 + q0 + w * 16 + lr] != 0;

    float mrow = -3.0e38f, lsum = 0.f;
    f4 o[4] = {};

    const _Float16* __restrict__ Kp = Kh + (size_t)bh * 1536 * 64;
    const _Float16* __restrict__ Vp = Vt + (size_t)bh * 64 * 1536;

    // staging slots: idx = t + rep*256 in [0,512); r = idx>>3, kk = (idx&7)*8
    const int sr0 = t >> 3,        skk = (t & 7) * 8;
    const int sr1 = (t + 256) >> 3;

    h8 krg[2], vrg[2];
    krg[0] = *reinterpret_cast<const h8*>(&Kp[(size_t)sr0 * 64 + skk]);
    krg[1] = *reinterpret_cast<const h8*>(&Kp[(size_t)sr1 * 64 + skk]);
    vrg[0] = *reinterpret_cast<const h8*>(&Vp[(size_t)sr0 * 1536 + skk]);
    vrg[1] = *reinterpret_cast<const h8*>(&Vp[(size_t)sr1 * 1536 + skk]);
    *reinterpret_cast<h8*>(&Ks[sr0 * 72 + skk]) = krg[0];
    *reinterpret_cast<h8*>(&Ks[sr1 * 72 + skk]) = krg[1];
    *reinterpret_cast<h8*>(&Vs[sr0 * 72 + skk]) = vrg[0];
    *reinterpret_cast<h8*>(&Vs[sr1 * 72 + skk]) = vrg[1];

    for (int c0 = 0; c0 < 1536; c0 += 64) {
        __syncthreads();                       // staged K/V visible
        const bool more = (c0 + 64) < 1536;
        if (more) {                            // issue next-chunk loads early
            const int cn = c0 + 64;
            krg[0] = *reinterpret_cast<const h8*>(&Kp[(size_t)(cn + sr0) * 64 + skk]);
            krg[1] = *reinterpret_cast<const h8*>(&Kp[(size_t)(cn + sr1) * 64 + skk]);
            vrg[0] = *reinterpret_cast<const h8*>(&Vp[(size_t)sr0 * 1536 + cn + skk]);
            vrg[1] = *reinterpret_cast<const h8*>(&Vp[(size_t)sr1 * 1536 + cn + skk]);
        }

        // S^T = K Q^T : per kb, A = K[row=key][d], B = Q[col=q][d]
        f4 st[4] = {};
        __builtin_amdgcn_s_setprio(1);
#pragma unroll
        for (int kb = 0; kb < 4; kb++) {
            h8 ka0 = *reinterpret_cast<h8*>(&Ks[(kb * 16 + lr) * 72 + lk]);
            h8 ka1 = *reinterpret_cast<h8*>(&Ks[(kb * 16 + lr) * 72 + 32 + lk]);
            st[kb] = __builtin_amdgcn_mfma_f32_16x16x32_f16(ka0, qf0, st[kb], 0, 0, 0);
            st[kb] = __builtin_amdgcn_mfma_f32_16x16x32_f16(ka1, qf1, st[kb], 0, 0, 0);
        }
        __builtin_amdgcn_s_setprio(0);

        // lane-local softmax for q = lr; keys kb*16 + lg*4 + reg
        if (!msk) {
#pragma unroll
            for (int kb = 0; kb < 4; kb++) { st[kb][0] = NEGV; st[kb][1] = NEGV; st[kb][2] = NEGV; st[kb][3] = NEGV; }
        }
        float cm = fmaxf(fmaxf(fmaxf(st[0][0], st[0][1]), fmaxf(st[0][2], st[0][3])),
                         fmaxf(fmaxf(st[1][0], st[1][1]), fmaxf(st[1][2], st[1][3])));
        cm = fmaxf(cm, fmaxf(fmaxf(fmaxf(st[2][0], st[2][1]), fmaxf(st[2][2], st[2][3])),
                             fmaxf(fmaxf(st[3][0], st[3][1]), fmaxf(st[3][2], st[3][3]))));
        cm = fmaxf(cm, __shfl_xor(cm, 16));
        cm = fmaxf(cm, __shfl_xor(cm, 32));

        if (!__all(cm <= mrow + 8.0f)) {       // defer-max: rescale only on real growth
            const float mn = fmaxf(mrow, cm);
            const float sc = __builtin_amdgcn_exp2f(mrow - mn);
            mrow = mn;
            lsum *= sc;
#pragma unroll
            for (int dg = 0; dg < 4; dg++) o[dg] *= sc;
        }

        float rs = 0.f;
#pragma unroll
        for (int kb = 0; kb < 4; kb++) {
            const float p0 = __builtin_amdgcn_exp2f(st[kb][0] - mrow);
            const float p1 = __builtin_amdgcn_exp2f(st[kb][1] - mrow);
            const float p2 = __builtin_amdgcn_exp2f(st[kb][2] - mrow);
            const float p3 = __builtin_amdgcn_exp2f(st[kb][3] - mrow);
            rs += (p0 + p1) + (p2 + p3);
            h4 ph = { (_Float16)p0, (_Float16)p1, (_Float16)p2, (_Float16)p3 };
            *reinterpret_cast<h4*>(&Ps[(w * 16 + lr) * 72 + kb * 16 + lg * 4]) = ph;
        }
        rs += __shfl_xor(rs, 16);
        rs += __shfl_xor(rs, 32);
        lsum += rs;

        // O^T += V^T P : A = V^T[row=d][k], B = P[col=q][k]  (Ps rows wave-local)
        __builtin_amdgcn_s_setprio(1);
#pragma unroll
        for (int kb2 = 0; kb2 < 2; kb2++) {
            h8 pa = *reinterpret_cast<h8*>(&Ps[(w * 16 + lr) * 72 + kb2 * 32 + lk]);
#pragma unroll
            for (int dg = 0; dg < 4; dg++) {
                h8 va = *reinterpret_cast<h8*>(&Vs[(dg * 16 + lr) * 72 + kb2 * 32 + lk]);
                o[dg] = __builtin_amdgcn_mfma_f32_16x16x32_f16(va, pa, o[dg], 0, 0, 0);
            }
        }
        __builtin_amdgcn_s_setprio(0);

        __syncthreads();                       // all K/V reads done
        if (more) {                            // write-late: land next chunk
            *reinterpret_cast<h8*>(&Ks[sr0 * 72 + skk]) = krg[0];
            *reinterpret_cast<h8*>(&Ks[sr1 * 72 + skk]) = krg[1];
            *reinterpret_cast<h8*>(&Vs[sr0 * 72 + skk]) = vrg[0];
            *reinterpret_cast<h8*>(&Vs[sr1 * 72 + skk]) = vrg[1];
        }
    }

    // write O: lane holds O^T[d = dg*16+lg*4+reg][q=lr]
    const float inv = 1.f / lsum;
    const size_t row = (size_t)mod * 4096 + b * 512 + q0 + w * 16 + lr;
#pragma unroll
    for (int dg = 0; dg < 4; dg++) {
        h4 ov = { (_Float16)(o[dg][0] * inv), (_Float16)(o[dg][1] * inv),
                  (_Float16)(o[dg][2] * inv), (_Float16)(o[dg][3] * inv) };
        *reinterpret_cast<h4*>(&Oh[row * 512 + h * 64 + dg * 16 + lg * 4]) = ov;
    }
}

// ======================= output projection (f16 MFMA, f32 out) =======================
__global__ __launch_bounds__(256) void out_gemm_f16(
    const _Float16* __restrict__ Oh, const _Float16* __restrict__ Wot,
    float* __restrict__ out)
{
    const int mod = blockIdx.z;
    const _Float16* __restrict__ A  = Oh  + (size_t)mod * 4096 * 512;
    const _Float16* __restrict__ Bw = Wot + (size_t)mod * 512 * 512;
    float* __restrict__ C = out + (size_t)mod * 4096 * 512;

    __shared__ _Float16 As[128 * 40];
    __shared__ _Float16 Bs[128 * 40];

    const int t = threadIdx.x;
    const int brow = blockIdx.y * 128, bcol = blockIdx.x * 128;
    const int w = t >> 6, l = t & 63;
    const int wr = (w >> 1) * 64, wc = (w & 1) * 64;
    const int lr = l & 15, lk = (l >> 4) * 8, lg = l >> 4;

    const int sm0 = t >> 2,        skk = (t & 3) * 8;
    const int sm1 = (t + 256) >> 2;

    f4 acc[4][4] = {};
    h8 arg[2], brg[2];

    arg[0] = *reinterpret_cast<const h8*>(&A [(size_t)(brow + sm0) * 512 + skk]);
    arg[1] = *reinterpret_cast<const h8*>(&A [(size_t)(brow + sm1) * 512 + skk]);
    brg[0] = *reinterpret_cast<const h8*>(&Bw[(size_t)(bcol + sm0) * 512 + skk]);
    brg[1] = *reinterpret_cast<const h8*>(&Bw[(size_t)(bcol + sm1) * 512 + skk]);
    *reinterpret_cast<h8*>(&As[sm0 * 40 + skk]) = arg[0];
    *reinterpret_cast<h8*>(&As[sm1 * 40 + skk]) = arg[1];
    *reinterpret_cast<h8*>(&Bs[sm0 * 40 + skk]) = brg[0];
    *reinterpret_cast<h8*>(&Bs[sm1 * 40 + skk]) = brg[1];

    for (int k0 = 0; k0 < 512; k0 += 32) {
        __syncthreads();
        const bool more = (k0 + 32) < 512;
        if (more) {
            const int kn = k0 + 32;
            arg[0] = *reinterpret_cast<const h8*>(&A [(size_t)(brow + sm0) * 512 + kn + skk]);
            arg[1] = *reinterpret_cast<const h8*>(&A [(size_t)(brow + sm1) * 512 + kn + skk]);
            brg[0] = *reinterpret_cast<const h8*>(&Bw[(size_t)(bcol + sm0) * 512 + kn + skk]);
            brg[1] = *reinterpret_cast<const h8*>(&Bw[(size_t)(bcol + sm1) * 512 + kn + skk]);
        }
        h8 af[4], bf[4];
#pragma unroll
        for (int m = 0; m < 4; m++)
            af[m] = *reinterpret_cast<h8*>(&As[(wr + m * 16 + lr) * 40 + lk]);
#pragma unroll
        for (int n = 0; n < 4; n++)
            bf[n] = *reinterpret_cast<h8*>(&Bs[(wc + n * 16 + lr) * 40 + lk]);
        __builtin_amdgcn_s_setprio(1);
#pragma unroll
        for (int m = 0; m < 4; m++)
#pragma unroll
            for (int n = 0; n < 4; n++)
                acc[m][n] = __builtin_amdgcn_mfma_f32_16x16x32_f16(af[m], bf[n], acc[m][n], 0, 0, 0);
        __builtin_amdgcn_s_setprio(0);
        __syncthreads();
        if (more) {
            *reinterpret_cast<h8*>(&As[sm0 * 40 + skk]) = arg[0];
            *reinterpret_cast<h8*>(&As[sm1 * 40 + skk]) = arg[1];
            *reinterpret_cast<h8*>(&Bs[sm0 * 40 + skk]) = brg[0];
            *reinterpret_cast<h8*>(&Bs[sm1 * 40 + skk]) = brg[1];
        }
    }

#pragma unroll
    for (int m = 0; m < 4; m++) {
        const int rloc = wr + m * 16 + lg * 4;
#pragma unroll
        for (int reg = 0; reg < 4; reg++) {
            const size_t base = (size_t)(brow + rloc + reg) * 512 + bcol;
#pragma unroll
            for (int nn = 0; nn < 4; nn++)
                C[base + wc + nn * 16 + lr] = acc[m][nn][reg];
        }
    }
}

extern "C" void kernel_launch(void* const* d_in, const int* in_sizes, int n_in,
                              void* d_out, int out_size, void* d_ws, size_t ws_size,
                              hipStream_t stream)
{
    // interleaved inputs: x0,m0,Wqkv0,Wout0, x1,m1,Wqkv1,Wout1, x2,m2,Wqkv2,Wout2
    const float* x0  = (const float*)d_in[0];
    const int*   m0  = (const int*)  d_in[1];
    const float* Wq0 = (const float*)d_in[2];
    const float* Wo0 = (const float*)d_in[3];
    const float* x1  = (const float*)d_in[4];
    const int*   m1  = (const int*)  d_in[5];
    const float* Wq1 = (const float*)d_in[6];
    const float* Wo1 = (const float*)d_in[7];
    const float* x2  = (const float*)d_in[8];
    const int*   m2  = (const int*)  d_in[9];
    const float* Wq2 = (const float*)d_in[10];
    const float* Wo2 = (const float*)d_in[11];

    _Float16* xh  = (_Float16*)d_ws;       // 6291456
    _Float16* Wqt = xh  + 6291456;         // 2359296
    _Float16* Wot = Wqt + 2359296;         //  786432
    _Float16* Qh  = Wot + 786432;          // 6291456
    _Float16* Kh  = Qh  + 6291456;         // 6291456
    _Float16* Vt  = Kh  + 6291456;         // 6291456
    _Float16* Oh  = Vt  + 6291456;         // 6291456

    cvt_x <<<dim3(2048, 3), 256, 0, stream>>>(x0, x1, x2, xh);
    tr_cvt<<<dim3(48, 16, 3), 256, 0, stream>>>(Wq0, Wq1, Wq2, Wqt, 512, 1536);
    tr_cvt<<<dim3(16, 16, 3), 256, 0, stream>>>(Wo0, Wo1, Wo2, Wot, 512, 512);

    qkv_gemm_f16<<<dim3(12, 32, 3), 256, 0, stream>>>(xh, Wqt, Qh, Kh, Vt);
    attn_f16    <<<dim3(8, 64, 3), 256, 0, stream>>>(Qh, Kh, Vt, m0, m1, m2, Oh);
    out_gemm_f16<<<dim3(4, 32, 3), 256, 0, stream>>>(Oh, Wot, (float*)d_out);
}

// Round 4
// 230.697 us; speedup vs baseline: 4.6297x; 1.1557x over previous
//
#include <hip/hip_runtime.h>
#include <cstdint>
#include <cstddef>

#define NEGV  -1.0e9f
// 0.125 * log2(e): attention computed in exp2 units
#define QSCALE 0.18033688011112042f

typedef _Float16 h8 __attribute__((ext_vector_type(8)));
typedef _Float16 h4 __attribute__((ext_vector_type(4)));
typedef float    f4 __attribute__((ext_vector_type(4)));

// ---------------------------------------------------------------------------
// ws layout (f16 elements):
//  Wqt: [3][1536][512]  (W^T)   2359296
//  Wot: [3][512][512]   (W^T)    786432
//  Qh : [3][8][8][512][64] (q*QSCALE)  6291456
//  Kh : [8][8][1536][64]        6291456
//  Vt : [8][8][64][1536] (V^T)  6291456
//  Oh : [3][4096][512]          6291456
// ---------------------------------------------------------------------------

static __device__ inline h8 cvt8(float4 a, float4 b) {
    h8 r = { (_Float16)a.x, (_Float16)a.y, (_Float16)a.z, (_Float16)a.w,
             (_Float16)b.x, (_Float16)b.y, (_Float16)b.z, (_Float16)b.w };
    return r;
}

// ============== conversion: W [R][C] f32 -> W^T [C][R] f16 ==============
__global__ __launch_bounds__(256) void tr_cvt(
    const float* __restrict__ s0, const float* __restrict__ s1, const float* __restrict__ s2,
    _Float16* __restrict__ dst, int R, int C)
{
    const int mod = blockIdx.z;
    const float* __restrict__ s = (mod == 0) ? s0 : ((mod == 1) ? s1 : s2);
    _Float16* __restrict__ d = dst + (size_t)mod * R * C;
    const int c0 = blockIdx.x * 32, r0 = blockIdx.y * 32;
    __shared__ float tile[32][33];
    const int tr = threadIdx.x >> 3;
    const int tc = (threadIdx.x & 7) * 4;
    float4 v = *reinterpret_cast<const float4*>(&s[(size_t)(r0 + tr) * C + c0 + tc]);
    tile[tr][tc + 0] = v.x; tile[tr][tc + 1] = v.y; tile[tr][tc + 2] = v.z; tile[tr][tc + 3] = v.w;
    __syncthreads();
    h4 o = { (_Float16)tile[tc + 0][tr], (_Float16)tile[tc + 1][tr],
             (_Float16)tile[tc + 2][tr], (_Float16)tile[tc + 3][tr] };
    *reinterpret_cast<h4*>(&d[(size_t)(c0 + tr) * R + r0 + tc]) = o;
}

// ======================= QKV projection (f16 MFMA) =======================
// x(f32)[4096][512] @ Wqt^T -> Qh/Kh/Vt. 128x128 tile, BK=32, reg-prefetch,
// f32->f16 fused into A-staging, LDS-transpose epilogue for coalesced stores.
// grid (32 rows, 12 cols, 3): A-panel sharers (same bx) land on same XCD.
__global__ __launch_bounds__(256) void qkv_gemm_f16(
    const float* __restrict__ x0, const float* __restrict__ x1, const float* __restrict__ x2,
    const _Float16* __restrict__ Wqt,
    _Float16* __restrict__ Qh, _Float16* __restrict__ Kh, _Float16* __restrict__ Vt)
{
    const int mod = blockIdx.z;
    const float* __restrict__ A = (mod == 0) ? x0 : ((mod == 1) ? x1 : x2);
    const _Float16* __restrict__ Bw = Wqt + (size_t)mod * 1536 * 512;

    __shared__ _Float16 smem[2 * 128 * 40];
    _Float16* As = smem;                 // [m][k] stride 40
    _Float16* Bs = smem + 128 * 40;      // [n][k]

    const int t = threadIdx.x;
    const int brow = blockIdx.x * 128, bcol = blockIdx.y * 128;
    const int w = t >> 6, l = t & 63;
    const int wr = (w >> 1) * 64, wc = (w & 1) * 64;
    const int lr = l & 15, lk = (l >> 4) * 8, lg = l >> 4;

    const int sm0 = t >> 2, skk = (t & 3) * 8, sm1 = sm0 + 64;

    f4 acc[4][4] = {};
    float4 axr[2][2];
    h8 brg[2];

    axr[0][0] = *reinterpret_cast<const float4*>(&A[(size_t)(brow + sm0) * 512 + skk]);
    axr[0][1] = *reinterpret_cast<const float4*>(&A[(size_t)(brow + sm0) * 512 + skk + 4]);
    axr[1][0] = *reinterpret_cast<const float4*>(&A[(size_t)(brow + sm1) * 512 + skk]);
    axr[1][1] = *reinterpret_cast<const float4*>(&A[(size_t)(brow + sm1) * 512 + skk + 4]);
    brg[0] = *reinterpret_cast<const h8*>(&Bw[(size_t)(bcol + sm0) * 512 + skk]);
    brg[1] = *reinterpret_cast<const h8*>(&Bw[(size_t)(bcol + sm1) * 512 + skk]);
    *reinterpret_cast<h8*>(&As[sm0 * 40 + skk]) = cvt8(axr[0][0], axr[0][1]);
    *reinterpret_cast<h8*>(&As[sm1 * 40 + skk]) = cvt8(axr[1][0], axr[1][1]);
    *reinterpret_cast<h8*>(&Bs[sm0 * 40 + skk]) = brg[0];
    *reinterpret_cast<h8*>(&Bs[sm1 * 40 + skk]) = brg[1];

    for (int k0 = 0; k0 < 512; k0 += 32) {
        __syncthreads();
        const bool more = (k0 + 32) < 512;
        if (more) {
            const int kn = k0 + 32 + skk;
            axr[0][0] = *reinterpret_cast<const float4*>(&A[(size_t)(brow + sm0) * 512 + kn]);
            axr[0][1] = *reinterpret_cast<const float4*>(&A[(size_t)(brow + sm0) * 512 + kn + 4]);
            axr[1][0] = *reinterpret_cast<const float4*>(&A[(size_t)(brow + sm1) * 512 + kn]);
            axr[1][1] = *reinterpret_cast<const float4*>(&A[(size_t)(brow + sm1) * 512 + kn + 4]);
            brg[0] = *reinterpret_cast<const h8*>(&Bw[(size_t)(bcol + sm0) * 512 + k0 + 32 + skk]);
            brg[1] = *reinterpret_cast<const h8*>(&Bw[(size_t)(bcol + sm1) * 512 + k0 + 32 + skk]);
        }
        h8 af[4], bf[4];
#pragma unroll
        for (int m = 0; m < 4; m++)
            af[m] = *reinterpret_cast<h8*>(&As[(wr + m * 16 + lr) * 40 + lk]);
#pragma unroll
        for (int n = 0; n < 4; n++)
            bf[n] = *reinterpret_cast<h8*>(&Bs[(wc + n * 16 + lr) * 40 + lk]);
        __builtin_amdgcn_s_setprio(1);
#pragma unroll
        for (int m = 0; m < 4; m++)
#pragma unroll
            for (int n = 0; n < 4; n++)
                acc[m][n] = __builtin_amdgcn_mfma_f32_16x16x32_f16(af[m], bf[n], acc[m][n], 0, 0, 0);
        __builtin_amdgcn_s_setprio(0);
        __syncthreads();
        if (more) {
            *reinterpret_cast<h8*>(&As[sm0 * 40 + skk]) = cvt8(axr[0][0], axr[0][1]);
            *reinterpret_cast<h8*>(&As[sm1 * 40 + skk]) = cvt8(axr[1][0], axr[1][1]);
            *reinterpret_cast<h8*>(&Bs[sm0 * 40 + skk]) = brg[0];
            *reinterpret_cast<h8*>(&Bs[sm1 * 40 + skk]) = brg[1];
        }
    }

    const int sec = bcol >> 9;                    // 0=q 1=k 2=v
    const int b = brow >> 9;
    const int nbase = brow & 511;
    const int cbase = bcol - (sec << 9);

    if (sec == 2) {
        // V^T direct: 4 consecutive keys (reg) per h4 store
#pragma unroll
        for (int m = 0; m < 4; m++) {
            const int n = nbase + wr + m * 16 + lg * 4;
#pragma unroll
            for (int nn = 0; nn < 4; nn++) {
                const int cis = cbase + wc + nn * 16 + lr;
                const int hh = cis >> 6, d = cis & 63;
                h4 pv = { (_Float16)acc[m][nn][0], (_Float16)acc[m][nn][1],
                          (_Float16)acc[m][nn][2], (_Float16)acc[m][nn][3] };
                *reinterpret_cast<h4*>(&Vt[(((size_t)b * 8 + hh) * 64 + d) * 1536 + mod * 512 + n]) = pv;
            }
        }
    } else {
        // LDS-transpose -> coalesced h8 row stores (2 passes of 64 rows)
        const float scl = (sec == 0) ? QSCALE : 1.0f;
        _Float16 (*Ts)[136] = reinterpret_cast<_Float16(*)[136]>(smem);
#pragma unroll
        for (int pass = 0; pass < 2; pass++) {
            __syncthreads();
            if ((w >> 1) == pass) {
#pragma unroll
                for (int m = 0; m < 4; m++)
#pragma unroll
                    for (int nn = 0; nn < 4; nn++)
#pragma unroll
                        for (int reg = 0; reg < 4; reg++)
                            Ts[m * 16 + lg * 4 + reg][wc + nn * 16 + lr] =
                                (_Float16)(acc[m][nn][reg] * scl);
            }
            __syncthreads();
#pragma unroll
            for (int it = 0; it < 4; it++) {
                const int idx = t + it * 256;
                const int r = idx >> 4, c = (idx & 15) * 8;
                h8 v = *reinterpret_cast<h8*>(&Ts[r][c]);
                const int n = nbase + pass * 64 + r;
                const int cis = cbase + c;
                const int hh = cis >> 6, d = cis & 63;
                if (sec == 0)
                    *reinterpret_cast<h8*>(&Qh[((((size_t)mod * 8 + b) * 8 + hh) * 512 + n) * 64 + d]) = v;
                else
                    *reinterpret_cast<h8*>(&Kh[(((size_t)b * 8 + hh) * 1536 + mod * 512 + n) * 64 + d]) = v;
            }
        }
    }
}

// ======================= attention (swapped QK^T, lane-local softmax) =======================
// block: 512 thr = 8 waves; QBLK=128 (wave w owns 16 q rows). grid (bh, qtile, mod):
// bh in blockIdx.x -> all K/V sharers on one XCD (id%8 = bh%8).
__global__ __launch_bounds__(512) void attn_f16(
    const _Float16* __restrict__ Qh, const _Float16* __restrict__ Kh, const _Float16* __restrict__ Vt,
    const int* __restrict__ m0, const int* __restrict__ m1, const int* __restrict__ m2,
    _Float16* __restrict__ Oh)
{
    const int mod = blockIdx.z;
    const int bh = blockIdx.x, b = bh >> 3, h = bh & 7;
    const int q0 = blockIdx.y * 128;

    __shared__ _Float16 Ks[64 * 72];    // [key][d]
    __shared__ _Float16 Vs[64 * 72];    // [d][key]
    __shared__ _Float16 Ps[128 * 72];   // [q][key] (wave-local rows)

    const int t = threadIdx.x, w = t >> 6, l = t & 63;
    const int lr = l & 15, lg = l >> 4, lk = lg * 8;

    const _Float16* __restrict__ Qp = Qh + ((((size_t)mod * 8 + b) * 8 + h) * 512 + q0 + w * 16) * 64;
    h8 qf0 = *reinterpret_cast<const h8*>(&Qp[(size_t)lr * 64 + lk]);
    h8 qf1 = *reinterpret_cast<const h8*>(&Qp[(size_t)lr * 64 + 32 + lk]);

    const int* __restrict__ mk = (mod == 0) ? m0 : ((mod == 1) ? m1 : m2);
    const bool msk = mk[b * 512 + q0 + w * 16 + lr] != 0;

    float mrow = -3.0e38f, lsum = 0.f;
    f4 o[4] = {};

    const int sr = t >> 3, skk = (t & 7) * 8;       // 512 thr: sr 0..63
    const _Float16* __restrict__ kSrc = Kh + (size_t)bh * 1536 * 64 + (size_t)sr * 64 + skk;
    const _Float16* __restrict__ vSrc = Vt + (size_t)bh * 64 * 1536 + (size_t)sr * 1536 + skk;
    _Float16* kDst = &Ks[sr * 72 + skk];
    _Float16* vDst = &Vs[sr * 72 + skk];

    h8 krg = *reinterpret_cast<const h8*>(kSrc);
    h8 vrg = *reinterpret_cast<const h8*>(vSrc);
    *reinterpret_cast<h8*>(kDst) = krg;
    *reinterpret_cast<h8*>(vDst) = vrg;

    for (int c0 = 0; c0 < 1536; c0 += 64) {
        __syncthreads();                       // staged K/V visible
        const bool more = (c0 + 64) < 1536;
        if (more) {                            // issue next-chunk loads early
            krg = *reinterpret_cast<const h8*>(kSrc + (size_t)(c0 + 64) * 64);
            vrg = *reinterpret_cast<const h8*>(vSrc + (c0 + 64));
        }

        // S^T = K Q^T
        f4 st[4] = {};
        __builtin_amdgcn_s_setprio(1);
#pragma unroll
        for (int kb = 0; kb < 4; kb++) {
            h8 ka0 = *reinterpret_cast<h8*>(&Ks[(kb * 16 + lr) * 72 + lk]);
            h8 ka1 = *reinterpret_cast<h8*>(&Ks[(kb * 16 + lr) * 72 + 32 + lk]);
            st[kb] = __builtin_amdgcn_mfma_f32_16x16x32_f16(ka0, qf0, st[kb], 0, 0, 0);
            st[kb] = __builtin_amdgcn_mfma_f32_16x16x32_f16(ka1, qf1, st[kb], 0, 0, 0);
        }
        __builtin_amdgcn_s_setprio(0);

        if (!msk) {
#pragma unroll
            for (int kb = 0; kb < 4; kb++) { st[kb][0] = NEGV; st[kb][1] = NEGV; st[kb][2] = NEGV; st[kb][3] = NEGV; }
        }
        float cm = fmaxf(fmaxf(fmaxf(st[0][0], st[0][1]), fmaxf(st[0][2], st[0][3])),
                         fmaxf(fmaxf(st[1][0], st[1][1]), fmaxf(st[1][2], st[1][3])));
        cm = fmaxf(cm, fmaxf(fmaxf(fmaxf(st[2][0], st[2][1]), fmaxf(st[2][2], st[2][3])),
                             fmaxf(fmaxf(st[3][0], st[3][1]), fmaxf(st[3][2], st[3][3]))));
        cm = fmaxf(cm, __shfl_xor(cm, 16));
        cm = fmaxf(cm, __shfl_xor(cm, 32));

        if (!__all(cm <= mrow + 8.0f)) {       // defer-max
            const float mn = fmaxf(mrow, cm);
            const float sc = __builtin_amdgcn_exp2f(mrow - mn);
            mrow = mn;
            lsum *= sc;
#pragma unroll
            for (int dg = 0; dg < 4; dg++) o[dg] *= sc;
        }

        float rs = 0.f;
#pragma unroll
        for (int kb = 0; kb < 4; kb++) {
            const float p0 = __builtin_amdgcn_exp2f(st[kb][0] - mrow);
            const float p1 = __builtin_amdgcn_exp2f(st[kb][1] - mrow);
            const float p2 = __builtin_amdgcn_exp2f(st[kb][2] - mrow);
            const float p3 = __builtin_amdgcn_exp2f(st[kb][3] - mrow);
            rs += (p0 + p1) + (p2 + p3);
            h4 ph = { (_Float16)p0, (_Float16)p1, (_Float16)p2, (_Float16)p3 };
            *reinterpret_cast<h4*>(&Ps[(w * 16 + lr) * 72 + kb * 16 + lg * 4]) = ph;
        }
        rs += __shfl_xor(rs, 16);
        rs += __shfl_xor(rs, 32);
        lsum += rs;

        // O^T += V^T P (Ps rows wave-local: in-wave DS order suffices)
        __builtin_amdgcn_s_setprio(1);
#pragma unroll
        for (int kb2 = 0; kb2 < 2; kb2++) {
            h8 pa = *reinterpret_cast<h8*>(&Ps[(w * 16 + lr) * 72 + kb2 * 32 + lk]);
#pragma unroll
            for (int dg = 0; dg < 4; dg++) {
                h8 va = *reinterpret_cast<h8*>(&Vs[(dg * 16 + lr) * 72 + kb2 * 32 + lk]);
                o[dg] = __builtin_amdgcn_mfma_f32_16x16x32_f16(va, pa, o[dg], 0, 0, 0);
            }
        }
        __builtin_amdgcn_s_setprio(0);

        __syncthreads();                       // all K/V reads done
        if (more) {                            // write-late
            *reinterpret_cast<h8*>(kDst) = krg;
            *reinterpret_cast<h8*>(vDst) = vrg;
        }
    }

    const float inv = 1.f / lsum;
    const size_t row = (size_t)mod * 4096 + b * 512 + q0 + w * 16 + lr;
#pragma unroll
    for (int dg = 0; dg < 4; dg++) {
        h4 ov = { (_Float16)(o[dg][0] * inv), (_Float16)(o[dg][1] * inv),
                  (_Float16)(o[dg][2] * inv), (_Float16)(o[dg][3] * inv) };
        *reinterpret_cast<h4*>(&Oh[row * 512 + h * 64 + dg * 16 + lg * 4]) = ov;
    }
}

// ======================= output projection (f16 MFMA, f32 out) =======================
__global__ __launch_bounds__(256) void out_gemm_f16(
    const _Float16* __restrict__ Oh, const _Float16* __restrict__ Wot,
    float* __restrict__ out)
{
    const int mod = blockIdx.z;
    const _Float16* __restrict__ A  = Oh  + (size_t)mod * 4096 * 512;
    const _Float16* __restrict__ Bw = Wot + (size_t)mod * 512 * 512;
    float* __restrict__ C = out + (size_t)mod * 4096 * 512;

    __shared__ _Float16 As[128 * 40];
    __shared__ _Float16 Bs[128 * 40];

    const int t = threadIdx.x;
    const int brow = blockIdx.x * 128, bcol = blockIdx.y * 128;
    const int w = t >> 6, l = t & 63;
    const int wr = (w >> 1) * 64, wc = (w & 1) * 64;
    const int lr = l & 15, lk = (l >> 4) * 8, lg = l >> 4;

    const int sm0 = t >> 2, skk = (t & 3) * 8, sm1 = sm0 + 64;

    f4 acc[4][4] = {};
    h8 arg[2], brg[2];

    arg[0] = *reinterpret_cast<const h8*>(&A [(size_t)(brow + sm0) * 512 + skk]);
    arg[1] = *reinterpret_cast<const h8*>(&A [(size_t)(brow + sm1) * 512 + skk]);
    brg[0] = *reinterpret_cast<const h8*>(&Bw[(size_t)(bcol + sm0) * 512 + skk]);
    brg[1] = *reinterpret_cast<const h8*>(&Bw[(size_t)(bcol + sm1) * 512 + skk]);
    *reinterpret_cast<h8*>(&As[sm0 * 40 + skk]) = arg[0];
    *reinterpret_cast<h8*>(&As[sm1 * 40 + skk]) = arg[1];
    *reinterpret_cast<h8*>(&Bs[sm0 * 40 + skk]) = brg[0];
    *reinterpret_cast<h8*>(&Bs[sm1 * 40 + skk]) = brg[1];

    for (int k0 = 0; k0 < 512; k0 += 32) {
        __syncthreads();
        const bool more = (k0 + 32) < 512;
        if (more) {
            const int kn = k0 + 32 + skk;
            arg[0] = *reinterpret_cast<const h8*>(&A [(size_t)(brow + sm0) * 512 + kn]);
            arg[1] = *reinterpret_cast<const h8*>(&A [(size_t)(brow + sm1) * 512 + kn]);
            brg[0] = *reinterpret_cast<const h8*>(&Bw[(size_t)(bcol + sm0) * 512 + kn]);
            brg[1] = *reinterpret_cast<const h8*>(&Bw[(size_t)(bcol + sm1) * 512 + kn]);
        }
        h8 af[4], bf[4];
#pragma unroll
        for (int m = 0; m < 4; m++)
            af[m] = *reinterpret_cast<h8*>(&As[(wr + m * 16 + lr) * 40 + lk]);
#pragma unroll
        for (int n = 0; n < 4; n++)
            bf[n] = *reinterpret_cast<h8*>(&Bs[(wc + n * 16 + lr) * 40 + lk]);
        __builtin_amdgcn_s_setprio(1);
#pragma unroll
        for (int m = 0; m < 4; m++)
#pragma unroll
            for (int n = 0; n < 4; n++)
                acc[m][n] = __builtin_amdgcn_mfma_f32_16x16x32_f16(af[m], bf[n], acc[m][n], 0, 0, 0);
        __builtin_amdgcn_s_setprio(0);
        __syncthreads();
        if (more) {
            *reinterpret_cast<h8*>(&As[sm0 * 40 + skk]) = arg[0];
            *reinterpret_cast<h8*>(&As[sm1 * 40 + skk]) = arg[1];
            *reinterpret_cast<h8*>(&Bs[sm0 * 40 + skk]) = brg[0];
            *reinterpret_cast<h8*>(&Bs[sm1 * 40 + skk]) = brg[1];
        }
    }

#pragma unroll
    for (int m = 0; m < 4; m++) {
        const int rloc = wr + m * 16 + lg * 4;
#pragma unroll
        for (int reg = 0; reg < 4; reg++) {
            const size_t base = (size_t)(brow + rloc + reg) * 512 + bcol;
#pragma unroll
            for (int nn = 0; nn < 4; nn++)
                C[base + wc + nn * 16 + lr] = acc[m][nn][reg];
        }
    }
}

extern "C" void kernel_launch(void* const* d_in, const int* in_sizes, int n_in,
                              void* d_out, int out_size, void* d_ws, size_t ws_size,
                              hipStream_t stream)
{
    // interleaved inputs: x0,m0,Wqkv0,Wout0, x1,m1,Wqkv1,Wout1, x2,m2,Wqkv2,Wout2
    const float* x0  = (const float*)d_in[0];
    const int*   m0  = (const int*)  d_in[1];
    const float* Wq0 = (const float*)d_in[2];
    const float* Wo0 = (const float*)d_in[3];
    const float* x1  = (const float*)d_in[4];
    const int*   m1  = (const int*)  d_in[5];
    const float* Wq1 = (const float*)d_in[6];
    const float* Wo1 = (const float*)d_in[7];
    const float* x2  = (const float*)d_in[8];
    const int*   m2  = (const int*)  d_in[9];
    const float* Wq2 = (const float*)d_in[10];
    const float* Wo2 = (const float*)d_in[11];

    _Float16* Wqt = (_Float16*)d_ws;       // 2359296
    _Float16* Wot = Wqt + 2359296;         //  786432
    _Float16* Qh  = Wot + 786432;          // 6291456
    _Float16* Kh  = Qh  + 6291456;         // 6291456
    _Float16* Vt  = Kh  + 6291456;         // 6291456
    _Float16* Oh  = Vt  + 6291456;         // 6291456

    tr_cvt<<<dim3(48, 16, 3), 256, 0, stream>>>(Wq0, Wq1, Wq2, Wqt, 512, 1536);
    tr_cvt<<<dim3(16, 16, 3), 256, 0, stream>>>(Wo0, Wo1, Wo2, Wot, 512, 512);

    qkv_gemm_f16<<<dim3(32, 12, 3), 256, 0, stream>>>(x0, x1, x2, Wqt, Qh, Kh, Vt);
    attn_f16    <<<dim3(64, 4, 3), 512, 0, stream>>>(Qh, Kh, Vt, m0, m1, m2, Oh);
    out_gemm_f16<<<dim3(32, 4, 3), 256, 0, stream>>>(Oh, Wot, (float*)d_out);
}